// Round 1
// baseline (274.589 us; speedup 1.0000x reference)
//
#include <hip/hip_runtime.h>
#include <cstdint>
#include <cstddef>

typedef __attribute__((ext_vector_type(8))) short bf16x8;
typedef __attribute__((ext_vector_type(4))) float f32x4;
typedef __attribute__((ext_vector_type(4))) int   i32x4;

#define C_CH   256
#define NBOX   512      // B*N
#define FCDIM  1024
#define K1     12544    // C*7*7
#define OUTC   93

__device__ __forceinline__ unsigned short f2bf(float f) {
    unsigned u = __float_as_uint(f);
    u += 0x7fffu + ((u >> 16) & 1u);      // RNE
    return (unsigned short)(u >> 16);
}

// ---------------- cast f32 -> bf16, 8 elems/thread ----------------
__global__ __launch_bounds__(256) void cast_bf16_kernel(
    const float* __restrict__ in, short* __restrict__ out, int n8)
{
    int i = blockIdx.x * 256 + threadIdx.x;
    if (i >= n8) return;
    const float4* p = (const float4*)(in + (size_t)i * 8);
    float4 a = p[0], b = p[1];
    union { unsigned short s[8]; i32x4 v; } u;
    u.s[0] = f2bf(a.x); u.s[1] = f2bf(a.y); u.s[2] = f2bf(a.z); u.s[3] = f2bf(a.w);
    u.s[4] = f2bf(b.x); u.s[5] = f2bf(b.y); u.s[6] = f2bf(b.z); u.s[7] = f2bf(b.w);
    *(i32x4*)(out + (size_t)i * 8) = u.v;
}

// ---------------- ROI align: one block per box ----------------
__global__ __launch_bounds__(256) void roi_kernel(
    const float* __restrict__ f0, const float* __restrict__ f1,
    const float* __restrict__ f2, const float* __restrict__ f3,
    const float* __restrict__ bbox, const int* __restrict__ aid,
    short* __restrict__ pooled)
{
    int bn = blockIdx.x;            // b*256 + n
    int b  = bn >> 8;
    float y = bbox[bn*4+0], x = bbox[bn*4+1], h = bbox[bn*4+2], w = bbox[bn*4+3];
    int level = aid[bn] / 3;        // 0..3
    const float* fsrc = (level == 0) ? f0 : (level == 1) ? f1 : (level == 2) ? f2 : f3;
    int H = 128 >> level;           // square feature maps
    float scale = 1.0f / (float)(4 << level);
    const float* fp = fsrc + (size_t)b * C_CH * H * H;

    float t0 = (y - 0.5f*h) * scale - 0.5f;
    float l0 = (x - 0.5f*w) * scale - 0.5f;
    float bh = h * scale * (1.0f/7.0f);
    float bw = w * scale * (1.0f/7.0f);

    __shared__ int   y0s[14], y1s[14], x0s[14], x1s[14];
    __shared__ float wys[14], wxs[14];
    int t = threadIdx.x;
    if (t < 14) {
        float g = ((float)t + 0.5f) * 0.5f;
        float v = t0 + bh * g;
        v = fminf(fmaxf(v, 0.0f), (float)(H-1));
        int i0 = (int)v;
        y0s[t] = i0; y1s[t] = min(i0 + 1, H - 1); wys[t] = v - (float)i0;
    } else if (t < 28) {
        int p = t - 14;
        float g = ((float)p + 0.5f) * 0.5f;
        float v = l0 + bw * g;
        v = fminf(fmaxf(v, 0.0f), (float)(H-1));
        int i0 = (int)v;
        x0s[p] = i0; x1s[p] = min(i0 + 1, H - 1); wxs[p] = v - (float)i0;
    }
    __syncthreads();

    for (int oi = t; oi < K1; oi += 256) {
        int c  = oi / 49;
        int s  = oi - c * 49;
        int py = s / 7, px = s - py * 7;
        const float* fc = fp + (size_t)c * H * H;
        float acc = 0.0f;
        #pragma unroll
        for (int ry = 0; ry < 2; ry++) {
            int sy = py*2 + ry;
            const float* r0 = fc + y0s[sy] * H;
            const float* r1 = fc + y1s[sy] * H;
            float wy = wys[sy];
            #pragma unroll
            for (int rx = 0; rx < 2; rx++) {
                int sx = px*2 + rx;
                int xa = x0s[sx], xb = x1s[sx];
                float wx = wxs[sx];
                float v00 = r0[xa], v01 = r0[xb], v10 = r1[xa], v11 = r1[xb];
                float top = v00 * (1.0f - wx) + v01 * wx;
                float bot = v10 * (1.0f - wx) + v11 * wx;
                acc += top * (1.0f - wy) + bot * wy;
            }
        }
        pooled[(size_t)bn * K1 + oi] = (short)f2bf(acc * 0.25f);
    }
}

// ---------------- bf16 MFMA GEMM, 64x64 tile, split-K ----------------
// A:[M=512][K] bf16, Bt:[N=1024][K] bf16 (weights, K-contiguous), part:[z][512][1024] f32
#define LDT 40   // padded LDS row (shorts)
__global__ __launch_bounds__(256) void gemm_bf16_splitk(
    const short* __restrict__ A, const short* __restrict__ Bt,
    float* __restrict__ part, int K, int KC)
{
    __shared__ short As[64 * LDT];
    __shared__ short Bs[64 * LDT];
    const int M = NBOX, N = FCDIM;
    int tn = blockIdx.x, tm = blockIdx.y, z = blockIdx.z;
    int t = threadIdx.x;
    int w = t >> 6, lane = t & 63;
    int row4 = t >> 2, ks = t & 3;           // staging: 64 rows x 4 k-slots of 8
    int m0 = tm * 64, n0 = tn * 64;
    int k0 = z * KC, kend = k0 + KC;

    const short* pa = A  + (size_t)(m0 + row4) * K + ks * 8;
    const short* pb = Bt + (size_t)(n0 + row4) * K + ks * 8;
    short* sa = &As[row4 * LDT + ks * 8];
    short* sb = &Bs[row4 * LDT + ks * 8];

    int wr = (w >> 1) * 32, wc = (w & 1) * 32;
    int fr = lane & 15, kg = lane >> 4;
    const short* ra0 = &As[(wr + fr) * LDT + kg * 8];
    const short* rb0 = &Bs[(wc + fr) * LDT + kg * 8];

    f32x4 acc[2][2] = {};
    for (int k = k0; k < kend; k += 32) {
        i32x4 va = *(const i32x4*)(pa + k);
        i32x4 vb = *(const i32x4*)(pb + k);
        __syncthreads();                       // prior iter's LDS reads done
        *(i32x4*)sa = va;
        *(i32x4*)sb = vb;
        __syncthreads();
        bf16x8 a0 = *(const bf16x8*)(ra0);
        bf16x8 a1 = *(const bf16x8*)(ra0 + 16 * LDT);
        bf16x8 b0 = *(const bf16x8*)(rb0);
        bf16x8 b1 = *(const bf16x8*)(rb0 + 16 * LDT);
        acc[0][0] = __builtin_amdgcn_mfma_f32_16x16x32_bf16(a0, b0, acc[0][0], 0, 0, 0);
        acc[0][1] = __builtin_amdgcn_mfma_f32_16x16x32_bf16(a0, b1, acc[0][1], 0, 0, 0);
        acc[1][0] = __builtin_amdgcn_mfma_f32_16x16x32_bf16(a1, b0, acc[1][0], 0, 0, 0);
        acc[1][1] = __builtin_amdgcn_mfma_f32_16x16x32_bf16(a1, b1, acc[1][1], 0, 0, 0);
    }
    float* base = part + (size_t)z * M * N;
    #pragma unroll
    for (int i = 0; i < 2; i++)
        #pragma unroll
        for (int j = 0; j < 2; j++)
            #pragma unroll
            for (int r = 0; r < 4; r++) {
                int row = m0 + wr + i * 16 + kg * 4 + r;
                int col = n0 + wc + j * 16 + fr;
                base[(size_t)row * N + col] = acc[i][j][r];
            }
}

// ---------------- BatchNorm over rows (512) + ReLU; sums split-K partials ----------------
// block owns 32 columns; 8 row-groups x 32 cols = 256 threads
__global__ __launch_bounds__(256) void bn_kernel(
    const float* __restrict__ part, float* __restrict__ xsum,
    const float* __restrict__ g, const float* __restrict__ be,
    short* __restrict__ out_bf, float* __restrict__ out_f)
{
    int tc = threadIdx.x & 31;
    int tr = threadIdx.x >> 5;
    int c  = blockIdx.x * 32 + tc;
    const size_t P = (size_t)NBOX * FCDIM;

    float s = 0.0f, q = 0.0f;
    for (int r = tr; r < NBOX; r += 8) {
        size_t o = (size_t)r * FCDIM + c;
        float x = part[o] + part[o + P] + part[o + 2*P] + part[o + 3*P];
        xsum[o] = x;
        s += x; q += x * x;
    }
    __shared__ float Ss[8][32], Sq[8][32], sca[32], shf[32];
    Ss[tr][tc] = s; Sq[tr][tc] = q;
    __syncthreads();
    if (tr == 0) {
        float S = 0.0f, Q = 0.0f;
        #pragma unroll
        for (int i = 0; i < 8; i++) { S += Ss[i][tc]; Q += Sq[i][tc]; }
        float mu  = S * (1.0f / NBOX);
        float var = Q * (1.0f / NBOX) - mu * mu;
        float a = g[c] * rsqrtf(var + 1e-5f);
        sca[tc] = a;
        shf[tc] = be[c] - mu * a;
    }
    __syncthreads();
    float a = sca[tc], bsh = shf[tc];
    for (int r = tr; r < NBOX; r += 8) {
        size_t o = (size_t)r * FCDIM + c;
        float x = fmaxf(xsum[o] * a + bsh, 0.0f);
        if (out_bf) out_bf[o] = (short)f2bf(x);
        else        out_f[o]  = x;
    }
}

// ---------------- pred GEMV + bbox decode + softmax/sigmoid ----------------
__global__ __launch_bounds__(128) void pred_kernel(
    const float* __restrict__ xin, const float* __restrict__ pw,
    const float* __restrict__ pb, const float* __restrict__ bbox,
    const int* __restrict__ aid, const float* __restrict__ zp,
    float* __restrict__ out)
{
    int bn = blockIdx.x;
    int t  = threadIdx.x;
    __shared__ float xs[FCDIM];
    __shared__ float pr[OUTC];
    for (int i = t; i < FCDIM; i += 128)
        xs[i] = xin[(size_t)bn * FCDIM + i];
    __syncthreads();

    float z = zp[bn];
    if (t < OUTC) {
        const float* wrow = pw + (size_t)t * FCDIM;
        float acc = 0.0f;
        for (int k = 0; k < FCDIM; k += 4) {
            float4 w4 = *(const float4*)(wrow + k);
            acc += xs[k] * w4.x + xs[k+1] * w4.y + xs[k+2] * w4.z + xs[k+3] * w4.w;
        }
        pr[t] = (acc + pb[t]) * z;
    }
    __syncthreads();

    if (t < OUTC) {
        float y = bbox[bn*4+0], x = bbox[bn*4+1], h = bbox[bn*4+2], w = bbox[bn*4+3];
        int lvl = aid[bn] / 3;
        float st = 4.0f * exp2f((float)lvl * z);
        float o;
        if (t < 24) {
            int k = t / 6, j = t - k * 6;
            const float* d = &pr[5 + k * 6];
            switch (j) {
                case 0:  o = y + d[0] * h;  break;
                case 1:  o = x + d[1] * w;  break;
                case 2:  o = d[4] * st;     break;
                case 3:  o = h * expf(d[2]); break;
                case 4:  o = w * expf(d[3]); break;
                default: o = expf(d[5]) * st; break;
            }
        } else if (t < 29) {
            float m = pr[0];
            #pragma unroll
            for (int i = 1; i < 5; i++) m = fmaxf(m, pr[i]);
            float den = 0.0f;
            #pragma unroll
            for (int i = 0; i < 5; i++) den += expf(pr[i] - m);
            o = expf(pr[t - 24] - m) / den;
        } else if (t < 61) {
            int i = t - 29, k = i >> 3;
            const float* qq = &pr[29 + k * 8];
            float m = qq[0];
            #pragma unroll
            for (int ii = 1; ii < 8; ii++) m = fmaxf(m, qq[ii]);
            float den = 0.0f;
            #pragma unroll
            for (int ii = 0; ii < 8; ii++) den += expf(qq[ii] - m);
            o = expf(pr[t] - m) / den;
        } else {
            o = 1.0f / (1.0f + expf(-pr[t])) * 0.6f - 0.3f;
        }
        out[(size_t)bn * OUTC + t] = o;
    }
}

extern "C" void kernel_launch(void* const* d_in, const int* in_sizes, int n_in,
                              void* d_out, int out_size, void* d_ws, size_t ws_size,
                              hipStream_t stream)
{
    const float* f0   = (const float*)d_in[0];
    const float* f1   = (const float*)d_in[1];
    const float* f2   = (const float*)d_in[2];
    const float* f3   = (const float*)d_in[3];
    const float* bbox = (const float*)d_in[4];
    const int*   aid  = (const int*)d_in[5];
    const float* zp   = (const float*)d_in[6];
    const float* fc1w = (const float*)d_in[7];
    const float* bn1g = (const float*)d_in[9];
    const float* bn1b = (const float*)d_in[10];
    const float* fc2w = (const float*)d_in[11];
    const float* bn2g = (const float*)d_in[13];
    const float* bn2b = (const float*)d_in[14];
    const float* pw   = (const float*)d_in[15];
    const float* pb   = (const float*)d_in[16];
    float* out = (float*)d_out;

    // workspace layout (bytes)
    char* ws = (char*)d_ws;
    short* pooled = (short*)(ws);                      // 512*12544*2   = 12,845,056
    short* w1     = (short*)(ws + 12845056);           // 1024*12544*2  = 25,690,112
    short* w2     = (short*)(ws + 38535168);           // 1024*1024*2   =  2,097,152
    float* part   = (float*)(ws + 40632320);           // 4*512*1024*4  =  8,388,608
    float* xsum   = (float*)(ws + 49020928);           // 512*1024*4    =  2,097,152
    short* x1n    = (short*)(ws + 51118080);           // 512*1024*2    =  1,048,576
    float* x2n    = (float*)(ws + 52166656);           // 512*1024*4    =  2,097,152
    // total ~54.3 MB

    cast_bf16_kernel<<<(K1 * FCDIM / 8 + 255) / 256, 256, 0, stream>>>(fc1w, w1, K1 * FCDIM / 8);
    cast_bf16_kernel<<<(FCDIM * FCDIM / 8 + 255) / 256, 256, 0, stream>>>(fc2w, w2, FCDIM * FCDIM / 8);

    roi_kernel<<<NBOX, 256, 0, stream>>>(f0, f1, f2, f3, bbox, aid, pooled);

    dim3 g1(FCDIM / 64, NBOX / 64, 4);   // 16 x 8 x 4
    gemm_bf16_splitk<<<g1, 256, 0, stream>>>(pooled, w1, part, K1, K1 / 4);
    bn_kernel<<<FCDIM / 32, 256, 0, stream>>>(part, xsum, bn1g, bn1b, x1n, nullptr);

    gemm_bf16_splitk<<<g1, 256, 0, stream>>>(x1n, w2, part, FCDIM, FCDIM / 4);
    bn_kernel<<<FCDIM / 32, 256, 0, stream>>>(part, xsum, bn2g, bn2b, nullptr, x2n);

    pred_kernel<<<NBOX, 128, 0, stream>>>(x2n, pw, pb, bbox, aid, zp, out);
}